// Round 1
// baseline (112.438 us; speedup 1.0000x reference)
//
#include <hip/hip_runtime.h>
#include <cmath>

// SpikingLayer forward:
//   vmem[t] = sum_{k=0..99} kf[k] * x[t-k],  kf[k] = exp(-k/10) - exp(-k/5)
//   serial scan: v = vmem - r; n = max(floor(v),0); r = (r+n)*alpha
// Exact sliding recurrence for the truncated exponential FIR:
//   S[t] = a*S[t-1] + x[t] - a^100 * x[t-100];  vmem = S_mem - S_syn
// All state in double so floor() decisions match the float64 numpy reference
// (output is integer-valued; a flipped floor is an absmax error of 1.0).

#define T_LEN 1024
#define CHUNKS 256        // T_LEN / 4
#define DELAY_CHUNKS 25   // 100 / 4  (delay is float4-aligned)

__global__ __launch_bounds__(64, 1)
void spiking_fwd(const float* __restrict__ x,
                 const float* __restrict__ rk,
                 float* __restrict__ out,
                 double a_m, double a_s, double am100, double as100)
{
    const int neuron = blockIdx.x * 64 + threadIdx.x;
    const float4* __restrict__ xr  = (const float4*)(x   + (size_t)neuron * T_LEN);
    float4* __restrict__       outr = (float4*)(out + (size_t)neuron * T_LEN);

    // alpha = ref_kernel[1] / ref_kernel[0], from the actual input array
    const double alpha = (double)rk[1] / (double)rk[0];

    double s_m = 0.0, s_s = 0.0, r = 0.0;

    const float4 zero4 = make_float4(0.f, 0.f, 0.f, 0.f);

    // 4-deep prefetch pipeline for the current-x stream (covers HBM latency:
    // one 64B line = 4 chunks), 2-deep for the 100-step-delayed stream
    // (same row 400B earlier -> L1/L2 hit).
    float4 c0 = xr[0], c1 = xr[1], c2 = xr[2], c3 = xr[3];
    float4 d0 = zero4, d1 = zero4;

#define STEP(XC, XD, OO) do {                                  \
        double xc = (double)(XC);                              \
        double xd = (double)(XD);                              \
        s_m = fma(a_m, s_m, fma(-am100, xd, xc));              \
        s_s = fma(a_s, s_s, fma(-as100, xd, xc));              \
        double v = (s_m - s_s) - r;                            \
        double n = fmax(floor(v), 0.0);                        \
        r = (r + n) * alpha;                                   \
        OO = (float)n;                                         \
    } while (0)

    for (int c = 0; c < CHUNKS; ++c) {
        float4 cur = c0;
        c0 = c1; c1 = c2; c2 = c3;
        c3 = (c + 4 < CHUNKS) ? xr[c + 4] : zero4;

        float4 del = d0;
        d0 = d1;
        d1 = (c + 2 >= DELAY_CHUNKS) ? xr[c + 2 - DELAY_CHUNKS] : zero4;

        float4 o;
        STEP(cur.x, del.x, o.x);
        STEP(cur.y, del.y, o.y);
        STEP(cur.z, del.z, o.z);
        STEP(cur.w, del.w, o.w);
        outr[c] = o;
    }
#undef STEP
}

extern "C" void kernel_launch(void* const* d_in, const int* in_sizes, int n_in,
                              void* d_out, int out_size, void* d_ws, size_t ws_size,
                              hipStream_t stream)
{
    const float* x  = (const float*)d_in[0];   // binary_input (1,32,1024,1024)
    const float* rk = (const float*)d_in[2];   // ref_kernel (100,)
    float* out = (float*)d_out;                // spikes (32,1024,1024) fp32

    const int neurons = in_sizes[0] / T_LEN;   // 32768

    const double a_m   = std::exp(-0.1);   // exp(-dt/tau_mem)
    const double a_s   = std::exp(-0.2);   // exp(-dt/tau_syn)
    const double am100 = std::exp(-10.0);  // a_m^100
    const double as100 = std::exp(-20.0);  // a_s^100

    dim3 grid(neurons / 64), block(64);
    hipLaunchKernelGGL(spiking_fwd, grid, block, 0, stream,
                       x, rk, out, a_m, a_s, am100, as100);
}

// Round 2
// 96.755 us; speedup vs baseline: 1.1621x; 1.1621x over previous
//
#include <hip/hip_runtime.h>
#include <cmath>

// SpikingLayer forward, LDS-tiled version.
//   vmem[t] = sum_{k=0..99} kf[k]*x[t-k], kf[k] = exp(-k/10) - exp(-k/5)
//   Exact sliding recurrence: S[t] = a*S[t-1] + x[t] - a^100*x[t-100]
//   vmem = S_mem - S_syn; then serial floor/refractory scan (f64 so floor
//   decisions match the float64 numpy reference exactly; round-1 absmax = 0).
//
// Block = 64 threads = 64 neurons (ONE wave: no __syncthreads needed, LDS
// ordering is wave-internal program order). Input staged coalesced through a
// 6-deep LDS ring of [64 x 32]-step tiles; the 100-step-delayed stream is
// served from ring slots c-4 / c-3 (delay 100 = 3*32 + 4). Slots 2..5 are
// zeroed at start so tiles < 0 read as zero. Output staged through LDS and
// stored coalesced (fixes round-1's 210 MB WRITE_SIZE).

#define T_LEN 1024
#define TILE 32
#define NT (T_LEN / TILE)       // 32 tiles
#define GRP 8                   // float4 groups per tile
#define ROWPAD 36               // words per LDS row (32 data + 4 pad)
#define SLOT (64 * ROWPAD)      // 2304 words per tile slot
#define NSLOT 6                 // ring depth: {c-4, c-3, c-2, c-1, c, c+1}

__global__ __launch_bounds__(64, 2)
void spiking_fwd(const float* __restrict__ x,
                 const float* __restrict__ rk,
                 float* __restrict__ out,
                 double a_m, double a_s, double am100, double as100)
{
    __shared__ float lds[(NSLOT + 1) * SLOT];   // 6 in-ring + 1 out = 63 KB
    float* const outb = lds + NSLOT * SLOT;

    const int l    = threadIdx.x;
    const int n0   = blockIdx.x * 64;
    const int rowq = l >> 3;     // 0..7  (staging row group)
    const int colq = l & 7;      // 0..7  (staging f4 column)

    const double alpha = (double)rk[1] / (double)rk[0];

    // zero ring slots 2..5: they are read as "tile < 0" by the delayed path
    for (int k = 0; k < 36; ++k) {
        int w = 2 * SLOT + (k * 64 + l) * 4;
        *(float4*)(lds + w) = make_float4(0.f, 0.f, 0.f, 0.f);
    }

    // stage tile 0 into slot 0 (coalesced: 8 lanes cover 128B per row)
    {
        const float* src = x + (size_t)n0 * T_LEN + colq * 4;
        #pragma unroll
        for (int j = 0; j < 8; ++j) {
            int rr = rowq + 8 * j;
            float4 v = *(const float4*)(src + (size_t)rr * T_LEN);
            *(float4*)(lds + rr * ROWPAD + colq * 4) = v;
        }
    }

    double s_m = 0.0, s_s = 0.0, r = 0.0;
    int s_cur = 0;
    float* const og = out + (size_t)n0 * T_LEN;

#define STEP(XC, XD, OO) do {                                  \
        double xc = (double)(XC);                              \
        double xd = (double)(XD);                              \
        s_m = fma(a_m, s_m, fma(-am100, xd, xc));              \
        s_s = fma(a_s, s_s, fma(-as100, xd, xc));              \
        double v = (s_m - s_s) - r;                            \
        double n = fmax(floor(v), 0.0);                        \
        r = (r + n) * alpha;                                   \
        OO = (float)n;                                         \
    } while (0)

    for (int c = 0; c < NT; ++c) {
        // ---- issue prefetch loads for tile c+1 (land ~1 full tile later) ----
        float4 gph[8];
        const bool pf = (c + 1 < NT);
        if (pf) {
            const float* src = x + (size_t)n0 * T_LEN + (c + 1) * TILE + colq * 4;
            #pragma unroll
            for (int j = 0; j < 8; ++j)
                gph[j] = *(const float4*)(src + (size_t)(rowq + 8 * j) * T_LEN);
        }

        int s_d3 = s_cur - 3; if (s_d3 < 0) s_d3 += NSLOT;
        int s_d4 = s_cur - 4; if (s_d4 < 0) s_d4 += NSLOT;
        int s_nxt = s_cur + 1; if (s_nxt == NSLOT) s_nxt = 0;

        const float* curb = lds + s_cur * SLOT + l * ROWPAD;
        const float* d3b  = lds + s_d3 * SLOT + l * ROWPAD;
        const float* d4b  = lds + s_d4 * SLOT + l * ROWPAD;
        float*       ob   = outb + l * ROWPAD;

        // ---- serial scan over this tile (32 steps, f64 chain) ----
        #pragma unroll
        for (int gq = 0; gq < GRP; ++gq) {
            float4 xc4 = *(const float4*)(curb + gq * 4);
            // delayed group: t-100 -> tile c-4 group 7 (gq==0) else tile c-3 group gq-1
            float4 xd4 = (gq == 0) ? *(const float4*)(d4b + 7 * 4)
                                   : *(const float4*)(d3b + (gq - 1) * 4);
            float4 o;
            STEP(xc4.x, xd4.x, o.x);
            STEP(xc4.y, xd4.y, o.y);
            STEP(xc4.z, xd4.z, o.z);
            STEP(xc4.w, xd4.w, o.w);
            *(float4*)(ob + gq * 4) = o;
        }

        // ---- flush out tile (coalesced full-line stores) ----
        {
            float* dst = og + c * TILE + colq * 4;
            #pragma unroll
            for (int j = 0; j < 8; ++j) {
                int rr = rowq + 8 * j;
                float4 v = *(const float4*)(outb + rr * ROWPAD + colq * 4);
                *(float4*)(dst + (size_t)rr * T_LEN) = v;
            }
        }

        // ---- write prefetched tile into ring slot c+1 ----
        if (pf) {
            float* dstl = lds + s_nxt * SLOT + colq * 4;
            #pragma unroll
            for (int j = 0; j < 8; ++j)
                *(float4*)(dstl + (rowq + 8 * j) * ROWPAD) = gph[j];
        }
        s_cur = s_nxt;
    }
#undef STEP
}

extern "C" void kernel_launch(void* const* d_in, const int* in_sizes, int n_in,
                              void* d_out, int out_size, void* d_ws, size_t ws_size,
                              hipStream_t stream)
{
    const float* x  = (const float*)d_in[0];   // binary_input (1,32,1024,1024)
    const float* rk = (const float*)d_in[2];   // ref_kernel (100,)
    float* out = (float*)d_out;                // spikes (32,1024,1024) fp32

    const int neurons = in_sizes[0] / T_LEN;   // 32768

    const double a_m   = std::exp(-0.1);   // exp(-dt/tau_mem)
    const double a_s   = std::exp(-0.2);   // exp(-dt/tau_syn)
    const double am100 = std::exp(-10.0);  // a_m^100
    const double as100 = std::exp(-20.0);  // a_s^100

    dim3 grid(neurons / 64), block(64);
    hipLaunchKernelGGL(spiking_fwd, grid, block, 0, stream,
                       x, rk, out, a_m, a_s, am100, as100);
}

// Round 5
// 68.868 us; speedup vs baseline: 1.6327x; 1.4049x over previous
//
#include <hip/hip_runtime.h>
#include <cmath>

// SpikingLayer forward — producer/consumer decomposition (exact).
//
// vmem[t] = sum_{k=0}^{99} (am^k - as^k) x[t-k] is a FINITE FIR -> the linear
// part is exactly time-chunkable (zero-history start W steps early: error
// a^(W+1)*|s| <= e^-28.9*10 ~ 3e-12, contractive). The nonlinear refractory
// scan (floor) is NEVER chunked: one consumer wave runs it exactly,
// sequentially, in f64, with the same op order as the round-2 kernel that
// scored absmax 0.0.
//
// Round-5 fixes vs round-4 (both rounds failed at absmax exactly 1.0):
//  * BUG: (__float_as_uint(1.0f)>>30)&1 == 0 -> every delayed spike bit was
//    dropped (a ~4.5e-5 vmem perturbation -> thousands of floor flips).
//    Fixed: xf != 0.0f.
//  * Producer reverted from 2nd-order direct form to the dual 1st-order
//    recurrences (bit-identical to the gold round-2 math for chunk 0).
//
// Workgroup = 256 threads = 4 waves, owns 64 neurons x T=1024:
//   waves 0-2 (producers): s_m/s_s recurrences, delayed tap from packed-bit
//     register FIFO (x is binary). Chunks [0,352) [352,704) [704,1024),
//     warmup 288 for P1/P2. f64 vmem tiles (32 steps) -> 4-deep LDS ring.
//   wave 3 (consumer): v=vm-r; n=max(floor(v),0); r=(r+n)*alpha. Exact.
//     Output staged in LDS, stored coalesced.
// Handshake: ready[tile] / cons_prog acquire-release atomics in LDS (ran
// race-free in round 4). 76.9 KB LDS -> 2 WG/CU -> 2 waves/SIMD.

#define T_LEN   1024
#define NT      32                    // 32-step tiles
#define RING    4
#define VROWB   264                   // vmem row stride bytes
#define VSLOTB  (64 * VROWB)          // 16896 B per ring slot
#define OROWW   36                    // out staging row stride (words)
#define LDS_OUT (RING * VSLOTB)                 // 67584
#define LDS_FLG (LDS_OUT + 64 * OROWW * 4)      // 76800
#define LDS_TOT (LDS_FLG + (NT + 1) * 4)        // 76932

__global__ __launch_bounds__(256, 2)
void spiking_fwd(const float* __restrict__ x, const float* __restrict__ rk,
                 float* __restrict__ out,
                 double a_m, double a_s, double am100, double as100)
{
    __shared__ __align__(16) unsigned char lds[LDS_TOT];
    int* const flags = (int*)(lds + LDS_FLG);   // [0..31]=ready, [32]=cons_prog
    int* const consp = flags + NT;

    const int tid = threadIdx.x, wid = tid >> 6, lane = tid & 63;
    const int n0 = blockIdx.x * 64;

    if (tid <= NT) flags[tid] = 0;
    __syncthreads();

    if (wid < 3) {
        // ================= producer =================
        const int S = (wid == 0) ? 0   : (wid == 1 ? 352 : 704);
        const int E = (wid == 0) ? 352 : (wid == 1 ? 704 : 1024);
        const int W = (wid == 0) ? 0   : 288;
        const int t0 = S - W;
        const int warmTiles = W >> 5;
        const int totTiles  = (E - t0) >> 5;
        const int gt0 = t0 >> 5;
        const float* xrow = x + (size_t)(n0 + lane) * T_LEN + t0;

        double s_m = 0.0, s_s = 0.0, vn = 0.0;
        unsigned b0 = 0, b1 = 0, b2 = 0, b3 = 0;  // bit FIFO: tiles li-4..li-1

        float cur[32], nxt[32];
        #pragma unroll
        for (int j = 0; j < 8; ++j) {
            float4 t = *(const float4*)(xrow + j * 4);
            cur[4*j+0]=t.x; cur[4*j+1]=t.y; cur[4*j+2]=t.z; cur[4*j+3]=t.w;
        }

#define PSTEP(K) do {                                              \
            const float xf = cur[(K)];                             \
            const double xc = (double)xf;                          \
            const unsigned bd = (wmask >> (K)) & 1u;               \
            s_m = fma(a_m, s_m, xc - (bd ? am100 : 0.0));          \
            s_s = fma(a_s, s_s, xc - (bd ? as100 : 0.0));          \
            vn = s_m - s_s;                                        \
            if (xf != 0.0f) bcur |= (1u << (K));                   \
        } while (0)

        for (int li = 0; li < totTiles; ++li) {
            if (li + 1 < totTiles) {                 // prefetch next tile
                #pragma unroll
                for (int j = 0; j < 8; ++j) {
                    float4 t = *(const float4*)(xrow + (li + 1) * 32 + j * 4);
                    nxt[4*j+0]=t.x; nxt[4*j+1]=t.y; nxt[4*j+2]=t.z; nxt[4*j+3]=t.w;
                }
            }
            // step t = t0+li*32+K needs x[t-100]: K<4 -> tile li-4 bit 28+K,
            // K>=4 -> tile li-3 bit K-4.
            const unsigned wmask = (b0 >> 28) | (b1 << 4);
            unsigned bcur = 0;
            const int gt = gt0 + li;

            if (li >= warmTiles) {
                while (gt - __hip_atomic_load(consp, __ATOMIC_ACQUIRE,
                                              __HIP_MEMORY_SCOPE_WORKGROUP) >= RING)
                    __builtin_amdgcn_s_sleep(1);
                unsigned char* vrow = lds + (size_t)(gt & (RING-1)) * VSLOTB + lane * VROWB;
                #pragma unroll
                for (int k = 0; k < 32; ++k) {
                    PSTEP(k);
                    *(double*)(vrow + k * 8) = vn;
                }
                __hip_atomic_store(&flags[gt], 1, __ATOMIC_RELEASE,
                                   __HIP_MEMORY_SCOPE_WORKGROUP);
            } else {
                #pragma unroll
                for (int k = 0; k < 32; ++k) { PSTEP(k); }
            }
            b0 = b1; b1 = b2; b2 = b3; b3 = bcur;
            #pragma unroll
            for (int i = 0; i < 32; ++i) cur[i] = nxt[i];
        }
#undef PSTEP
    } else {
        // ================= consumer (exact r-scan) =================
        const double alpha = (double)rk[1] / (double)rk[0];
        float* const og = out + (size_t)n0 * T_LEN;
        float* const ob = (float*)(lds + LDS_OUT);
        const int colq = lane & 7, rowq = lane >> 3;
        double r = 0.0;

        for (int gt = 0; gt < NT; ++gt) {
            while (!__hip_atomic_load(&flags[gt], __ATOMIC_ACQUIRE,
                                      __HIP_MEMORY_SCOPE_WORKGROUP))
                __builtin_amdgcn_s_sleep(1);

            const unsigned char* vrow = lds + (size_t)(gt & (RING-1)) * VSLOTB + lane * VROWB;
            double vm[32];
            #pragma unroll
            for (int k = 0; k < 32; ++k)
                vm[k] = *(const double*)(vrow + k * 8);

            float* orow = ob + lane * OROWW;
            #pragma unroll
            for (int k = 0; k < 32; ++k) {
                double v = vm[k] - r;                 // same op order as gold
                double n = fmax(floor(v), 0.0);
                r = (r + n) * alpha;
                orow[k] = (float)n;
            }
            __hip_atomic_store(consp, gt + 1, __ATOMIC_RELEASE,
                               __HIP_MEMORY_SCOPE_WORKGROUP);

            // coalesced flush: 8 neurons x 128B per sweep
            #pragma unroll
            for (int j = 0; j < 8; ++j) {
                const int nn = rowq + 8 * j;
                float4 t = *(const float4*)(ob + nn * OROWW + colq * 4);
                *(float4*)(og + (size_t)nn * T_LEN + gt * 32 + colq * 4) = t;
            }
        }
    }
}

extern "C" void kernel_launch(void* const* d_in, const int* in_sizes, int n_in,
                              void* d_out, int out_size, void* d_ws, size_t ws_size,
                              hipStream_t stream)
{
    const float* x  = (const float*)d_in[0];   // binary_input (1,32,1024,1024)
    const float* rk = (const float*)d_in[2];   // ref_kernel (100,)
    float* out = (float*)d_out;                // spikes (32,1024,1024) f32

    const int neurons = in_sizes[0] / T_LEN;   // 32768

    const double a_m   = std::exp(-0.1);       // exp(-dt/tau_mem)
    const double a_s   = std::exp(-0.2);       // exp(-dt/tau_syn)
    const double am100 = std::exp(-10.0);
    const double as100 = std::exp(-20.0);

    dim3 grid(neurons / 64), block(256);
    hipLaunchKernelGGL(spiking_fwd, grid, block, 0, stream,
                       x, rk, out, a_m, a_s, am100, as100);
}